// Round 19
// baseline (120.187 us; speedup 1.0000x reference)
//
#include <hip/hip_runtime.h>
#include <hip/hip_bf16.h>

typedef __attribute__((ext_vector_type(8))) short bf16x8;
typedef __attribute__((ext_vector_type(4))) float f32x4;
typedef __attribute__((ext_vector_type(16))) float f32x16;

#define LOG2E 1.4426950408889634f
#define SCALE_F (0.125f * LOG2E)

__device__ inline unsigned short f2bf(float f) {
  union { float f; unsigned u; } x; x.f = f;
  unsigned u = x.u;
  unsigned r = u + 0x7FFFu + ((u >> 16) & 1u);
  return (unsigned short)(r >> 16);
}

__device__ inline unsigned cvtpk(float lo, float hi) {
  unsigned r;
  asm("v_cvt_pk_bf16_f32 %0, %1, %2" : "=v"(r) : "v"(lo), "v"(hi));
  return r;
}

__device__ inline void gload16(const unsigned short* g, unsigned short* l) {
  __builtin_amdgcn_global_load_lds(
      (const __attribute__((address_space(1))) unsigned int*)g,
      (__attribute__((address_space(3))) unsigned int*)l, 16, 0, 0);
}

// pack 8 consecutive-key P values (f32, swapped-QKT acc layout) into a PV B-fragment.
template <int J>
__device__ inline bf16x8 pack_pfrag(f32x16 p) {
  int X, Y, Z, W;
  asm("v_cvt_pk_bf16_f32 %0, %1, %2" : "=v"(X) : "v"(p[J + 0]), "v"(p[J + 1]));
  asm("v_cvt_pk_bf16_f32 %0, %1, %2" : "=v"(Y) : "v"(p[J + 2]), "v"(p[J + 3]));
  asm("v_cvt_pk_bf16_f32 %0, %1, %2" : "=v"(Z) : "v"(p[J + 4]), "v"(p[J + 5]));
  asm("v_cvt_pk_bf16_f32 %0, %1, %2" : "=v"(W) : "v"(p[J + 6]), "v"(p[J + 7]));
  asm("v_permlane32_swap_b32 %0, %1" : "+v"(X), "+v"(Z));
  asm("v_permlane32_swap_b32 %0, %1" : "+v"(Y), "+v"(W));
  union { int w[4]; bf16x8 v; } u;
  u.w[0] = X; u.w[1] = Y; u.w[2] = Z; u.w[3] = W;
  return u.v;
}

// ---------------- fused prep: hs f32->bf16 + both weight transposes, one launch
__device__ inline void transpose_tile(const float* __restrict__ W,
                                      unsigned short* __restrict__ WT, int K, int N,
                                      int n0, int k0, int t,
                                      unsigned short (*Tl)[72]) {
#pragma unroll
  for (int i = 0; i < 4; ++i) {
    int idx = t + i * 256;
    int r = idx >> 4, c4 = (idx & 15) << 2;
    float4 v = *reinterpret_cast<const float4*>(&W[(size_t)(k0 + r) * N + n0 + c4]);
    Tl[c4 + 0][r] = f2bf(v.x);
    Tl[c4 + 1][r] = f2bf(v.y);
    Tl[c4 + 2][r] = f2bf(v.z);
    Tl[c4 + 3][r] = f2bf(v.w);
  }
  __syncthreads();
#pragma unroll
  for (int i = 0; i < 2; ++i) {
    int idx = t + i * 256;
    int rr = idx >> 3, cc = (idx & 7) << 3;
    *reinterpret_cast<int4*>(&WT[(size_t)(n0 + rr) * K + k0 + cc]) =
        *reinterpret_cast<const int4*>(&Tl[rr][cc]);
  }
}

__global__ __launch_bounds__(256) void prep_fused(
    const float* __restrict__ hs, unsigned short* __restrict__ hs_b,
    const float* __restrict__ w_attn, unsigned short* __restrict__ wT,
    const float* __restrict__ w_proj, unsigned short* __restrict__ pT) {
  __shared__ unsigned short Tl[64][72];
  const int bid = blockIdx.x, t = threadIdx.x;
  if (bid < 768) {
    transpose_tile(w_attn, wT, 1024, 3072, (bid % 48) * 64, (bid / 48) * 64, t, Tl);
  } else if (bid < 1024) {
    int r = bid - 768;
    transpose_tile(w_proj, pT, 1024, 1024, (r % 16) * 64, (r / 16) * 64, t, Tl);
  } else {
    int cb = bid - 1024;
#pragma unroll
    for (int j = 0; j < 4; ++j) {
      int i = cb * 1024 + j * 256 + t;
      float4 v = reinterpret_cast<const float4*>(hs)[i];
      ushort4 o;
      o.x = f2bf(v.x); o.y = f2bf(v.y); o.z = f2bf(v.z); o.w = f2bf(v.w);
      reinterpret_cast<ushort4*>(hs_b)[i] = o;
    }
  }
}

// ---------------- GEMM1: 256x192 tile, BK=64, 4-quadrant phases, read-once fragments.
// Epilogue: route output through LDS (reuse staging buffers) for coalesced 16B stores.
__global__ __launch_bounds__(512, 2) void gemm_qkv_8p(
    const unsigned short* __restrict__ A, const unsigned short* __restrict__ Bt,
    const float* __restrict__ bias,
    unsigned short* __restrict__ qw, unsigned short* __restrict__ kw,
    unsigned short* __restrict__ vtg) {
  __shared__ unsigned short smem_s[57344];  // 112 KB: Abuf 64K | Bbuf 48K; epi tile overlay
  unsigned short (*Abuf)[16384] = reinterpret_cast<unsigned short(*)[16384]>(smem_s);
  unsigned short (*Bbuf)[12288] = reinterpret_cast<unsigned short(*)[12288]>(&smem_s[32768]);
  unsigned short (*Tep)[200] = reinterpret_cast<unsigned short(*)[200]>(smem_s);
  const int t = threadIdx.x, lane = t & 63, wid = t >> 6;
  const int wm = wid >> 2, wn = wid & 3;
  const int orig = blockIdx.x;
  const int nid = (orig & 7) * 32 + (orig >> 3);
  const int mt = nid >> 4, nt = nid & 15;
  const int row0 = mt * 256, col0 = nt * 192;
  const int lr = lane & 15, kq = lane >> 4;
  const int srow_lo = lane >> 3;
  const int scg = (lane & 7) ^ srow_lo;
  const unsigned short* Ab = A + (size_t)row0 * 1024;
  const unsigned short* Bb = Bt + (size_t)col0 * 1024;
  f32x4 acc[8][3] = {};

#define SA8(bs, kt)                                                              \
  {                                                                              \
    const unsigned short* Ap = Ab + (kt) * 64;                                   \
    _Pragma("unroll") for (int i = 0; i < 4; ++i) {                              \
      int g = wid * 4 + i;                                                       \
      int rrel = g * 8 + srow_lo;                                                \
      gload16(&Ap[(size_t)rrel * 1024 + scg * 8], &Abuf[bs][g * 512]);           \
    }                                                                            \
  }
#define SB8(bs, kt)                                                              \
  {                                                                              \
    const unsigned short* Bp = Bb + (kt) * 64;                                   \
    _Pragma("unroll") for (int i = 0; i < 3; ++i) {                              \
      int g = wid * 3 + i;                                                       \
      int rrel = g * 8 + srow_lo;                                                \
      gload16(&Bp[(size_t)rrel * 1024 + scg * 8], &Bbuf[bs][g * 512]);           \
    }                                                                            \
  }
#define RDA(dst, mh)                                                             \
  _Pragma("unroll") for (int m = 0; m < 4; ++m)                                  \
  _Pragma("unroll") for (int ks = 0; ks < 2; ++ks) {                             \
    int row = wm * 128 + (mh) * 64 + m * 16 + lr;                                \
    dst[m][ks] = *reinterpret_cast<const bf16x8*>(                               \
        &Abuf[buf][row * 64 + (((ks * 4 + kq) ^ (row & 7)) << 3)]);              \
  }
#define RDB2(dst)                                                                \
  _Pragma("unroll") for (int n = 0; n < 2; ++n)                                  \
  _Pragma("unroll") for (int ks = 0; ks < 2; ++ks) {                             \
    int row = wn * 48 + n * 16 + lr;                                             \
    dst[n][ks] = *reinterpret_cast<const bf16x8*>(                               \
        &Bbuf[buf][row * 64 + (((ks * 4 + kq) ^ (row & 7)) << 3)]);              \
  }
#define RDB1(dst)                                                                \
  _Pragma("unroll") for (int ks = 0; ks < 2; ++ks) {                             \
    int row = wn * 48 + 32 + lr;                                                 \
    dst[0][ks] = *reinterpret_cast<const bf16x8*>(                               \
        &Bbuf[buf][row * 64 + (((ks * 4 + kq) ^ (row & 7)) << 3)]);              \
  }
#define QMM2(mh, afv, bfv)                                                       \
  _Pragma("unroll") for (int m = 0; m < 4; ++m)                                  \
  _Pragma("unroll") for (int n = 0; n < 2; ++n)                                  \
  _Pragma("unroll") for (int ks = 0; ks < 2; ++ks)                               \
    acc[(mh) * 4 + m][n] = __builtin_amdgcn_mfma_f32_16x16x32_bf16(              \
        afv[m][ks], bfv[n][ks], acc[(mh) * 4 + m][n], 0, 0, 0);
#define QMM1(mh, afv, bfv)                                                       \
  _Pragma("unroll") for (int m = 0; m < 4; ++m)                                  \
  _Pragma("unroll") for (int ks = 0; ks < 2; ++ks)                               \
    acc[(mh) * 4 + m][2] = __builtin_amdgcn_mfma_f32_16x16x32_bf16(              \
        afv[m][ks], bfv[0][ks], acc[(mh) * 4 + m][2], 0, 0, 0);
#define BAR8 __builtin_amdgcn_s_barrier();

  SA8(0, 0) SB8(0, 0)
  asm volatile("s_waitcnt vmcnt(0)" ::: "memory");
  BAR8
  __builtin_amdgcn_sched_barrier(0);

  for (int kt = 0; kt < 16; ++kt) {
    const int buf = kt & 1;
    bf16x8 af0[4][2], af1[4][2], bf0[2][2], bf1[1][2];
    RDA(af0, 0) RDB2(bf0)
    if (kt < 15) SA8(buf ^ 1, kt + 1)
    BAR8
    __builtin_amdgcn_s_setprio(1); QMM2(0, af0, bf0) __builtin_amdgcn_s_setprio(0);
    BAR8
    RDA(af1, 1)
    if (kt < 15) SB8(buf ^ 1, kt + 1)
    BAR8
    __builtin_amdgcn_s_setprio(1); QMM2(1, af1, bf0) __builtin_amdgcn_s_setprio(0);
    BAR8
    RDB1(bf1)
    BAR8
    __builtin_amdgcn_s_setprio(1); QMM1(0, af0, bf1) __builtin_amdgcn_s_setprio(0);
    BAR8
    __builtin_amdgcn_s_setprio(1); QMM1(1, af1, bf1) __builtin_amdgcn_s_setprio(0);
    if (kt < 15) { asm volatile("s_waitcnt vmcnt(0)" ::: "memory"); }
    BAR8
    __builtin_amdgcn_sched_barrier(0);
  }
#undef SA8
#undef SB8
#undef RDA
#undef RDB2
#undef RDB1
#undef QMM2
#undef QMM1
#undef BAR8

  // ---- coalesced epilogue: two passes (wm==0 -> rows 0-127, wm==1 -> rows 128-255)
  const int rbase = (lane >> 4) * 4;
#pragma unroll
  for (int p = 0; p < 2; ++p) {
    __syncthreads();
    if (wm == p) {
#pragma unroll
      for (int nn = 0; nn < 3; ++nn) {
        int c = col0 + wn * 48 + nn * 16 + lr;
        float bv = bias[c];
        float scl = (c < 1024) ? SCALE_F : 1.0f;  // pre-scale q for attn's bare exp2
#pragma unroll
        for (int mm = 0; mm < 8; ++mm) {
#pragma unroll
          for (int r = 0; r < 4; ++r) {
            int rl = mm * 16 + rbase + r;
            Tep[rl][wn * 48 + nn * 16 + lr] = f2bf((acc[mm][nn][r] + bv) * scl);
          }
        }
      }
    }
    __syncthreads();
    const int mbase = row0 + p * 128;
    const int b = mbase >> 11;
    const int sbase = mbase & 2047;
#pragma unroll
    for (int i = 0; i < 6; ++i) {
      int idx = t + i * 512;  // 0..3071 over 3 col-groups x 1024 store units
      int g = idx >> 10;
      int rem = idx & 1023;
      int cb = col0 + g * 64;
      int which = cb >> 10;
      int h = (cb >> 6) & 15;
      if (which < 2) {
        int row = rem >> 3, ch = rem & 7;
        int4 v = *reinterpret_cast<const int4*>(&Tep[row][g * 64 + ch * 8]);
        unsigned short* dst = (which == 0) ? qw : kw;
        *reinterpret_cast<int4*>(
            &dst[(((size_t)b * 16 + h) * 2048 + sbase + row) * 64 + ch * 8]) = v;
      } else {
        int dh = rem >> 4, kc = rem & 15;
        int key0 = kc * 8;
        union { unsigned short s[8]; int4 v; } u;
#pragma unroll
        for (int j = 0; j < 8; ++j) u.s[j] = Tep[key0 + j][g * 64 + dh];
        int kt2 = (sbase + key0) >> 6, key = (sbase + key0) & 63;
        *reinterpret_cast<int4*>(
            &vtg[(((size_t)(b * 16 + h) * 32 + kt2) * 64 + dh) * 64 + key]) = u.v;
      }
    }
  }
}

// ---------------- GEMM2: 128x128 tile, BK=64, 2-phase read-once, 8 waves (2M x 4N)
__global__ __launch_bounds__(512, 4) void gemm_proj_8p(
    const unsigned short* __restrict__ A, const unsigned short* __restrict__ Bt,
    const float* __restrict__ bias, float* __restrict__ out) {
  __shared__ unsigned short Abuf[2][8192];
  __shared__ unsigned short Bbuf[2][8192];
  const int t = threadIdx.x, lane = t & 63, wid = t >> 6;
  const int wm = wid >> 2, wn = wid & 3;
  const int orig = blockIdx.x;
  const int nid = (orig & 7) * 32 + (orig >> 3);
  const int row0 = (nid >> 3) * 128, col0 = (nid & 7) * 128;
  const int lr = lane & 15, kq = lane >> 4;
  const int srow_lo = lane >> 3;
  const int scg = (lane & 7) ^ srow_lo;
  const unsigned short* Ab = A + (size_t)row0 * 1024;
  const unsigned short* Bb = Bt + (size_t)col0 * 1024;
  f32x4 acc[4][2] = {};

#define SP(bs, kt)                                                               \
  {                                                                              \
    const unsigned short* Ap = Ab + (kt) * 64;                                   \
    const unsigned short* Bp = Bb + (kt) * 64;                                   \
    _Pragma("unroll") for (int i = 0; i < 2; ++i) {                              \
      int g = wid * 2 + i;                                                       \
      int rrel = g * 8 + srow_lo;                                                \
      gload16(&Ap[(size_t)rrel * 1024 + scg * 8], &Abuf[bs][g * 512]);           \
      gload16(&Bp[(size_t)rrel * 1024 + scg * 8], &Bbuf[bs][g * 512]);           \
    }                                                                            \
  }
#define RPA(dst, mh)                                                             \
  _Pragma("unroll") for (int m = 0; m < 2; ++m)                                  \
  _Pragma("unroll") for (int ks = 0; ks < 2; ++ks) {                             \
    int row = wm * 64 + (mh) * 32 + m * 16 + lr;                                 \
    dst[m][ks] = *reinterpret_cast<const bf16x8*>(                               \
        &Ac[row * 64 + (((ks * 4 + kq) ^ (row & 7)) << 3)]);                     \
  }
#define RPB(dst)                                                                 \
  _Pragma("unroll") for (int n = 0; n < 2; ++n)                                  \
  _Pragma("unroll") for (int ks = 0; ks < 2; ++ks) {                             \
    int row = wn * 32 + n * 16 + lr;                                             \
    dst[n][ks] = *reinterpret_cast<const bf16x8*>(                               \
        &Bc[row * 64 + (((ks * 4 + kq) ^ (row & 7)) << 3)]);                     \
  }
#define PMM(mh, afv, bfv)                                                        \
  _Pragma("unroll") for (int m = 0; m < 2; ++m)                                  \
  _Pragma("unroll") for (int n = 0; n < 2; ++n)                                  \
  _Pragma("unroll") for (int ks = 0; ks < 2; ++ks)                               \
    acc[(mh) * 2 + m][n] = __builtin_amdgcn_mfma_f32_16x16x32_bf16(              \
        afv[m][ks], bfv[n][ks], acc[(mh) * 2 + m][n], 0, 0, 0);
#define BARP __builtin_amdgcn_s_barrier();

  SP(0, 0)
  asm volatile("s_waitcnt vmcnt(0)" ::: "memory");
  BARP
  __builtin_amdgcn_sched_barrier(0);

  for (int kt = 0; kt < 16; ++kt) {
    const int buf = kt & 1;
    const unsigned short* Ac = Abuf[buf];
    const unsigned short* Bc = Bbuf[buf];
    bf16x8 af0[2][2], af1[2][2], bfv[2][2];
    RPA(af0, 0) RPB(bfv)
    if (kt < 15) SP(buf ^ 1, kt + 1)
    BARP
    __builtin_amdgcn_s_setprio(1); PMM(0, af0, bfv) __builtin_amdgcn_s_setprio(0);
    BARP
    RPA(af1, 1)
    BARP
    __builtin_amdgcn_s_setprio(1); PMM(1, af1, bfv) __builtin_amdgcn_s_setprio(0);
    if (kt < 15) { asm volatile("s_waitcnt vmcnt(0)" ::: "memory"); }
    BARP
    __builtin_amdgcn_sched_barrier(0);
  }
#undef SP
#undef RPA
#undef RPB
#undef PMM
#undef BARP

  const int rbase = (lane >> 4) * 4;
#pragma unroll
  for (int mm = 0; mm < 4; ++mm) {
#pragma unroll
    for (int nn = 0; nn < 2; ++nn) {
      int c = col0 + wn * 32 + nn * 16 + lr;
      float bv = bias[c];
#pragma unroll
      for (int r = 0; r < 4; ++r) {
        int m = row0 + wm * 64 + mm * 16 + rbase + r;
        out[(size_t)m * 1024 + c] = acc[mm][nn][r] + bv;
      }
    }
  }
}

// ---------------- Flash attention (round-16 known-good): 8 waves = 4 q-subtiles x 2 key-halves.
// K+V in LDS (full-rank swizzle), double-buffered, ONE barrier/iter, fixed-ref softmax.
__global__ __launch_bounds__(512, 4) void attn_kernel(
    const unsigned short* __restrict__ qw, const unsigned short* __restrict__ kw,
    const unsigned short* __restrict__ vtg, unsigned short* __restrict__ ow) {
  __shared__ char smem[65536];
  unsigned short* KV = (unsigned short*)smem;
  unsigned short* Ol = (unsigned short*)smem;
  float* EX = (float*)(smem + 18432);
  const int t = threadIdx.x, lane = t & 63, wid = t >> 6;
  const int half = wid >> 2, wq = wid & 3;
  const int l31 = lane & 31, hi = lane >> 5;
  const int orig = blockIdx.x + 16 * blockIdx.y;
  const int nid = (orig & 7) * 64 + (orig >> 3);
  const int qt = nid & 15, bh = nid >> 4;
  const int b = bh >> 4, h = bh & 15;
  const unsigned short* Qg = qw + (size_t)bh * 2048 * 64;
  const unsigned short* Kg = kw + (size_t)bh * 2048 * 64;
  const unsigned short* Vg = vtg + (size_t)bh * 32 * 4096;
  const int q0 = qt * 128 + wq * 32;

  bf16x8 qf[4];
#pragma unroll
  for (int kc = 0; kc < 4; ++kc)
    qf[kc] = *reinterpret_cast<const bf16x8*>(&Qg[(q0 + l31) * 64 + kc * 16 + hi * 8]);

  f32x16 oA = {0,0,0,0,0,0,0,0,0,0,0,0,0,0,0,0};
  f32x16 oB = {0,0,0,0,0,0,0,0,0,0,0,0,0,0,0,0};
  float lrun = 0.f;

  const int srow_lo = lane >> 3;
  const int scg0 = (lane & 7) ^ srow_lo;
  const int rsw = (l31 & 7) ^ ((l31 >> 3) & 3);

#define STAGE(buf, kt)                                                              \
  {                                                                                 \
    const unsigned short* Kt = Kg + (size_t)(kt) * 4096;                            \
    const unsigned short* Vs = Vg + (size_t)(kt) * 4096;                            \
    unsigned short* Kl = KV + half * 16384 + (buf) * 8192;                          \
    unsigned short* Vl = Kl + 4096;                                                 \
    _Pragma("unroll") for (int i = 0; i < 2; ++i) {                                 \
      int chunk = wq * 2 + i;                                                       \
      int row = chunk * 8 + srow_lo;                                                \
      int sc = (scg0 ^ (chunk & 3)) * 8;                                            \
      gload16(&Kt[row * 64 + sc], &Kl[chunk * 512]);                                \
      gload16(&Vs[row * 64 + sc], &Vl[chunk * 512]);                                \
    }                                                                               \
  }

  const int kt0 = half * 16;
  STAGE(0, kt0)

  for (int it = 0; it < 16; ++it) {
    const int cur = it & 1;
    asm volatile("s_waitcnt vmcnt(0)" ::: "memory");
    __builtin_amdgcn_s_barrier();
    if (it + 1 < 16) STAGE(cur ^ 1, kt0 + it + 1)
    const unsigned short* Kl = KV + half * 16384 + cur * 8192;
    const unsigned short* Vl = Kl + 4096;

    f32x16 sA = {0,0,0,0,0,0,0,0,0,0,0,0,0,0,0,0};
    f32x16 sB = {0,0,0,0,0,0,0,0,0,0,0,0,0,0,0,0};
    __builtin_amdgcn_s_setprio(1);
#pragma unroll
    for (int kc = 0; kc < 4; ++kc) {
      bf16x8 k0f = *reinterpret_cast<const bf16x8*>(
          &Kl[l31 * 64 + (((kc * 2 + hi) ^ rsw) << 3)]);
      bf16x8 k1f = *reinterpret_cast<const bf16x8*>(
          &Kl[(32 + l31) * 64 + (((kc * 2 + hi) ^ rsw) << 3)]);
      sA = __builtin_amdgcn_mfma_f32_32x32x16_bf16(k0f, qf[kc], sA, 0, 0, 0);
      sB = __builtin_amdgcn_mfma_f32_32x32x16_bf16(k1f, qf[kc], sB, 0, 0, 0);
    }
    __builtin_amdgcn_s_setprio(0);

    float rsv[16];
#pragma unroll
    for (int j = 0; j < 16; ++j) {
      float pa = exp2f(sA[j]);
      float pb = exp2f(sB[j]);
      sA[j] = pa; sB[j] = pb;
      rsv[j] = pa + pb;
    }
#pragma unroll
    for (int s = 8; s >= 1; s >>= 1)
#pragma unroll
      for (int j = 0; j < s; ++j) rsv[j] += rsv[j + s];
    lrun += rsv[0] + __shfl_xor(rsv[0], 32);

    bf16x8 pf0 = pack_pfrag<0>(sA);
    bf16x8 pf1 = pack_pfrag<8>(sA);
    bf16x8 pf2 = pack_pfrag<0>(sB);
    bf16x8 pf3 = pack_pfrag<8>(sB);

    __builtin_amdgcn_s_setprio(1);
#pragma unroll
    for (int c = 0; c < 4; ++c) {
      bf16x8 pf = (c == 0) ? pf0 : (c == 1) ? pf1 : (c == 2) ? pf2 : pf3;
      int g = c * 2 + hi;
      bf16x8 v0f = *reinterpret_cast<const bf16x8*>(
          &Vl[l31 * 64 + ((g ^ rsw) << 3)]);
      bf16x8 v1f = *reinterpret_cast<const bf16x8*>(
          &Vl[(32 + l31) * 64 + ((g ^ rsw) << 3)]);
      oA = __builtin_amdgcn_mfma_f32_32x32x16_bf16(v0f, pf, oA, 0, 0, 0);
      oB = __builtin_amdgcn_mfma_f32_32x32x16_bf16(v1f, pf, oB, 0, 0, 0);
    }
    __builtin_amdgcn_s_setprio(0);
  }
#undef STAGE

  __syncthreads();
  if (half == 1) {
    float* e = EX + ((size_t)(wq * 64 + lane)) * 34;
#pragma unroll
    for (int j = 0; j < 16; ++j) { e[j] = oA[j]; e[16 + j] = oB[j]; }
    e[32] = lrun;
  }
  __syncthreads();
  if (half == 0) {
    const float* e = EX + ((size_t)(wq * 64 + lane)) * 34;
    float linv = 1.0f / (lrun + e[32]);
    unsigned short* orow_l = Ol + (wq * 32 + l31) * 72;
#pragma unroll
    for (int g = 0; g < 4; ++g) {
      float a0 = (oA[4 * g + 0] + e[4 * g + 0]) * linv;
      float a1v = (oA[4 * g + 1] + e[4 * g + 1]) * linv;
      float a2v = (oA[4 * g + 2] + e[4 * g + 2]) * linv;
      float a3v = (oA[4 * g + 3] + e[4 * g + 3]) * linv;
      uint2 w0; w0.x = cvtpk(a0, a1v); w0.y = cvtpk(a2v, a3v);
      *reinterpret_cast<uint2*>(&orow_l[8 * g + 4 * hi]) = w0;
      float b0 = (oB[4 * g + 0] + e[16 + 4 * g + 0]) * linv;
      float b1v = (oB[4 * g + 1] + e[16 + 4 * g + 1]) * linv;
      float b2v = (oB[4 * g + 2] + e[16 + 4 * g + 2]) * linv;
      float b3v = (oB[4 * g + 3] + e[16 + 4 * g + 3]) * linv;
      uint2 w1; w1.x = cvtpk(b0, b1v); w1.y = cvtpk(b2v, b3v);
      *reinterpret_cast<uint2*>(&orow_l[32 + 8 * g + 4 * hi]) = w1;
    }
  }
  __syncthreads();
#pragma unroll
  for (int i = 0; i < 2; ++i) {
    int idx = t + i * 512;
    int q = idx >> 3, ch = idx & 7;
    int4 v = *reinterpret_cast<const int4*>(&Ol[q * 72 + ch * 8]);
    *reinterpret_cast<int4*>(
        &ow[(((size_t)b * 2048 + qt * 128 + q) * 16 + h) * 64 + ch * 8]) = v;
  }
}

extern "C" void kernel_launch(void* const* d_in, const int* in_sizes, int n_in,
                              void* d_out, int out_size, void* d_ws, size_t ws_size,
                              hipStream_t stream) {
  const float* hs = (const float*)d_in[0];
  const float* w_attn = (const float*)d_in[1];
  const float* b_attn = (const float*)d_in[2];
  const float* w_proj = (const float*)d_in[3];
  const float* b_proj = (const float*)d_in[4];
  float* out = (float*)d_out;

  const size_t HEAD = (size_t)2 * 16 * 2048 * 64;
  unsigned short* qw = (unsigned short*)d_ws;
  unsigned short* kw = qw + HEAD;
  unsigned short* vtg = kw + HEAD;
  unsigned short* hs_b = vtg + HEAD;
  unsigned short* ow = hs_b;
  unsigned short* wT = hs_b + HEAD;
  unsigned short* pT = wT + (size_t)3072 * 1024;

  prep_fused<<<dim3(2048), 256, 0, stream>>>(hs, hs_b, w_attn, wT, w_proj, pT);

  gemm_qkv_8p<<<dim3(256), 512, 0, stream>>>(hs_b, wT, b_attn, qw, kw, vtg);
  attn_kernel<<<dim3(16, 32), 512, 0, stream>>>(qw, kw, vtg, ow);
  gemm_proj_8p<<<dim3(256), 512, 0, stream>>>(ow, pT, b_proj, out);
}

// Round 20
// 114.813 us; speedup vs baseline: 1.0468x; 1.0468x over previous
//
#include <hip/hip_runtime.h>
#include <hip/hip_bf16.h>

typedef __attribute__((ext_vector_type(8))) short bf16x8;
typedef __attribute__((ext_vector_type(4))) float f32x4;
typedef __attribute__((ext_vector_type(16))) float f32x16;

#define LOG2E 1.4426950408889634f
#define SCALE_F (0.125f * LOG2E)

__device__ inline unsigned short f2bf(float f) {
  union { float f; unsigned u; } x; x.f = f;
  unsigned u = x.u;
  unsigned r = u + 0x7FFFu + ((u >> 16) & 1u);
  return (unsigned short)(r >> 16);
}

__device__ inline unsigned cvtpk(float lo, float hi) {
  unsigned r;
  asm("v_cvt_pk_bf16_f32 %0, %1, %2" : "=v"(r) : "v"(lo), "v"(hi));
  return r;
}

__device__ inline void gload16(const unsigned short* g, unsigned short* l) {
  __builtin_amdgcn_global_load_lds(
      (const __attribute__((address_space(1))) unsigned int*)g,
      (__attribute__((address_space(3))) unsigned int*)l, 16, 0, 0);
}

// pack 8 consecutive-key P values (f32, swapped-QKT acc layout) into a PV B-fragment.
template <int J>
__device__ inline bf16x8 pack_pfrag(f32x16 p) {
  int X, Y, Z, W;
  asm("v_cvt_pk_bf16_f32 %0, %1, %2" : "=v"(X) : "v"(p[J + 0]), "v"(p[J + 1]));
  asm("v_cvt_pk_bf16_f32 %0, %1, %2" : "=v"(Y) : "v"(p[J + 2]), "v"(p[J + 3]));
  asm("v_cvt_pk_bf16_f32 %0, %1, %2" : "=v"(Z) : "v"(p[J + 4]), "v"(p[J + 5]));
  asm("v_cvt_pk_bf16_f32 %0, %1, %2" : "=v"(W) : "v"(p[J + 6]), "v"(p[J + 7]));
  asm("v_permlane32_swap_b32 %0, %1" : "+v"(X), "+v"(Z));
  asm("v_permlane32_swap_b32 %0, %1" : "+v"(Y), "+v"(W));
  union { int w[4]; bf16x8 v; } u;
  u.w[0] = X; u.w[1] = Y; u.w[2] = Z; u.w[3] = W;
  return u.v;
}

// ---------------- fused prep: hs f32->bf16 + both weight transposes, one launch
__device__ inline void transpose_tile(const float* __restrict__ W,
                                      unsigned short* __restrict__ WT, int K, int N,
                                      int n0, int k0, int t,
                                      unsigned short (*Tl)[72]) {
#pragma unroll
  for (int i = 0; i < 4; ++i) {
    int idx = t + i * 256;
    int r = idx >> 4, c4 = (idx & 15) << 2;
    float4 v = *reinterpret_cast<const float4*>(&W[(size_t)(k0 + r) * N + n0 + c4]);
    Tl[c4 + 0][r] = f2bf(v.x);
    Tl[c4 + 1][r] = f2bf(v.y);
    Tl[c4 + 2][r] = f2bf(v.z);
    Tl[c4 + 3][r] = f2bf(v.w);
  }
  __syncthreads();
#pragma unroll
  for (int i = 0; i < 2; ++i) {
    int idx = t + i * 256;
    int rr = idx >> 3, cc = (idx & 7) << 3;
    *reinterpret_cast<int4*>(&WT[(size_t)(n0 + rr) * K + k0 + cc]) =
        *reinterpret_cast<const int4*>(&Tl[rr][cc]);
  }
}

__global__ __launch_bounds__(256) void prep_fused(
    const float* __restrict__ hs, unsigned short* __restrict__ hs_b,
    const float* __restrict__ w_attn, unsigned short* __restrict__ wT,
    const float* __restrict__ w_proj, unsigned short* __restrict__ pT) {
  __shared__ unsigned short Tl[64][72];
  const int bid = blockIdx.x, t = threadIdx.x;
  if (bid < 768) {
    transpose_tile(w_attn, wT, 1024, 3072, (bid % 48) * 64, (bid / 48) * 64, t, Tl);
  } else if (bid < 1024) {
    int r = bid - 768;
    transpose_tile(w_proj, pT, 1024, 1024, (r % 16) * 64, (r / 16) * 64, t, Tl);
  } else {
    int cb = bid - 1024;
#pragma unroll
    for (int j = 0; j < 4; ++j) {
      int i = cb * 1024 + j * 256 + t;
      float4 v = reinterpret_cast<const float4*>(hs)[i];
      ushort4 o;
      o.x = f2bf(v.x); o.y = f2bf(v.y); o.z = f2bf(v.z); o.w = f2bf(v.w);
      reinterpret_cast<ushort4*>(hs_b)[i] = o;
    }
  }
}

// ---------------- GEMM1: 256x192 tile, BK=64, 4-quadrant phases, read-once fragments.
__global__ __launch_bounds__(512, 2) void gemm_qkv_8p(
    const unsigned short* __restrict__ A, const unsigned short* __restrict__ Bt,
    const float* __restrict__ bias,
    unsigned short* __restrict__ qw, unsigned short* __restrict__ kw,
    unsigned short* __restrict__ vtg) {
  __shared__ unsigned short Abuf[2][16384];
  __shared__ unsigned short Bbuf[2][12288];
  const int t = threadIdx.x, lane = t & 63, wid = t >> 6;
  const int wm = wid >> 2, wn = wid & 3;
  const int orig = blockIdx.x;
  const int nid = (orig & 7) * 32 + (orig >> 3);
  const int mt = nid >> 4, nt = nid & 15;
  const int row0 = mt * 256, col0 = nt * 192;
  const int lr = lane & 15, kq = lane >> 4;
  const int srow_lo = lane >> 3;
  const int scg = (lane & 7) ^ srow_lo;
  const unsigned short* Ab = A + (size_t)row0 * 1024;
  const unsigned short* Bb = Bt + (size_t)col0 * 1024;
  f32x4 acc[8][3] = {};

#define SA8(bs, kt)                                                              \
  {                                                                              \
    const unsigned short* Ap = Ab + (kt) * 64;                                   \
    _Pragma("unroll") for (int i = 0; i < 4; ++i) {                              \
      int g = wid * 4 + i;                                                       \
      int rrel = g * 8 + srow_lo;                                                \
      gload16(&Ap[(size_t)rrel * 1024 + scg * 8], &Abuf[bs][g * 512]);           \
    }                                                                            \
  }
#define SB8(bs, kt)                                                              \
  {                                                                              \
    const unsigned short* Bp = Bb + (kt) * 64;                                   \
    _Pragma("unroll") for (int i = 0; i < 3; ++i) {                              \
      int g = wid * 3 + i;                                                       \
      int rrel = g * 8 + srow_lo;                                                \
      gload16(&Bp[(size_t)rrel * 1024 + scg * 8], &Bbuf[bs][g * 512]);           \
    }                                                                            \
  }
#define RDA(dst, mh)                                                             \
  _Pragma("unroll") for (int m = 0; m < 4; ++m)                                  \
  _Pragma("unroll") for (int ks = 0; ks < 2; ++ks) {                             \
    int row = wm * 128 + (mh) * 64 + m * 16 + lr;                                \
    dst[m][ks] = *reinterpret_cast<const bf16x8*>(                               \
        &Ac[row * 64 + (((ks * 4 + kq) ^ (row & 7)) << 3)]);                     \
  }
#define RDB2(dst)                                                                \
  _Pragma("unroll") for (int n = 0; n < 2; ++n)                                  \
  _Pragma("unroll") for (int ks = 0; ks < 2; ++ks) {                             \
    int row = wn * 48 + n * 16 + lr;                                             \
    dst[n][ks] = *reinterpret_cast<const bf16x8*>(                               \
        &Bc[row * 64 + (((ks * 4 + kq) ^ (row & 7)) << 3)]);                     \
  }
#define RDB1(dst)                                                                \
  _Pragma("unroll") for (int ks = 0; ks < 2; ++ks) {                             \
    int row = wn * 48 + 32 + lr;                                                 \
    dst[0][ks] = *reinterpret_cast<const bf16x8*>(                               \
        &Bc[row * 64 + (((ks * 4 + kq) ^ (row & 7)) << 3)]);                     \
  }
#define QMM2(mh, afv, bfv)                                                       \
  _Pragma("unroll") for (int m = 0; m < 4; ++m)                                  \
  _Pragma("unroll") for (int n = 0; n < 2; ++n)                                  \
  _Pragma("unroll") for (int ks = 0; ks < 2; ++ks)                               \
    acc[(mh) * 4 + m][n] = __builtin_amdgcn_mfma_f32_16x16x32_bf16(              \
        afv[m][ks], bfv[n][ks], acc[(mh) * 4 + m][n], 0, 0, 0);
#define QMM1(mh, afv, bfv)                                                       \
  _Pragma("unroll") for (int m = 0; m < 4; ++m)                                  \
  _Pragma("unroll") for (int ks = 0; ks < 2; ++ks)                               \
    acc[(mh) * 4 + m][2] = __builtin_amdgcn_mfma_f32_16x16x32_bf16(              \
        afv[m][ks], bfv[0][ks], acc[(mh) * 4 + m][2], 0, 0, 0);
#define BAR8 __builtin_amdgcn_s_barrier();

  SA8(0, 0) SB8(0, 0)
  asm volatile("s_waitcnt vmcnt(0)" ::: "memory");
  BAR8
  __builtin_amdgcn_sched_barrier(0);

  for (int kt = 0; kt < 16; ++kt) {
    const int buf = kt & 1;
    const unsigned short* Ac = Abuf[buf];
    const unsigned short* Bc = Bbuf[buf];
    bf16x8 af0[4][2], af1[4][2], bf0[2][2], bf1[1][2];
    RDA(af0, 0) RDB2(bf0)
    if (kt < 15) SA8(buf ^ 1, kt + 1)
    BAR8
    __builtin_amdgcn_s_setprio(1); QMM2(0, af0, bf0) __builtin_amdgcn_s_setprio(0);
    BAR8
    RDA(af1, 1)
    if (kt < 15) SB8(buf ^ 1, kt + 1)
    BAR8
    __builtin_amdgcn_s_setprio(1); QMM2(1, af1, bf0) __builtin_amdgcn_s_setprio(0);
    BAR8
    RDB1(bf1)
    BAR8
    __builtin_amdgcn_s_setprio(1); QMM1(0, af0, bf1) __builtin_amdgcn_s_setprio(0);
    BAR8
    __builtin_amdgcn_s_setprio(1); QMM1(1, af1, bf1) __builtin_amdgcn_s_setprio(0);
    if (kt < 15) { asm volatile("s_waitcnt vmcnt(0)" ::: "memory"); }
    BAR8
    __builtin_amdgcn_sched_barrier(0);
  }
#undef SA8
#undef SB8
#undef RDA
#undef RDB2
#undef RDB1
#undef QMM2
#undef QMM1
#undef BAR8

  const int rbase = (lane >> 4) * 4;
#pragma unroll
  for (int mm = 0; mm < 8; ++mm) {
#pragma unroll
    for (int nn = 0; nn < 3; ++nn) {
      int c = col0 + wn * 48 + nn * 16 + lr;
      int which = c >> 10;
      int d = c & 1023;
      int h = d >> 6, dh = d & 63;
      float bv = bias[c];
      int m0 = row0 + wm * 128 + mm * 16 + rbase;
      int b = m0 >> 11, s0 = m0 & 2047;
      if (which == 2) {
        int kt = s0 >> 6, key0 = s0 & 63;
        ushort4 pv;
        pv.x = f2bf(acc[mm][nn][0] + bv);
        pv.y = f2bf(acc[mm][nn][1] + bv);
        pv.z = f2bf(acc[mm][nn][2] + bv);
        pv.w = f2bf(acc[mm][nn][3] + bv);
        *reinterpret_cast<ushort4*>(
            &vtg[(((size_t)(b * 16 + h) * 32 + kt) * 64 + dh) * 64 + key0]) = pv;
      } else if (which == 1) {
#pragma unroll
        for (int r = 0; r < 4; ++r)
          kw[(((size_t)b * 16 + h) * 2048 + (s0 + r)) * 64 + dh] = f2bf(acc[mm][nn][r] + bv);
      } else {
#pragma unroll
        for (int r = 0; r < 4; ++r)
          qw[(((size_t)b * 16 + h) * 2048 + (s0 + r)) * 64 + dh] =
              f2bf((acc[mm][nn][r] + bv) * SCALE_F);
      }
    }
  }
}

// ---------------- GEMM2: 128x128 tile, BK=64, 2-phase read-once, 8 waves (2M x 4N)
__global__ __launch_bounds__(512, 4) void gemm_proj_8p(
    const unsigned short* __restrict__ A, const unsigned short* __restrict__ Bt,
    const float* __restrict__ bias, float* __restrict__ out) {
  __shared__ unsigned short Abuf[2][8192];
  __shared__ unsigned short Bbuf[2][8192];
  const int t = threadIdx.x, lane = t & 63, wid = t >> 6;
  const int wm = wid >> 2, wn = wid & 3;
  const int orig = blockIdx.x;
  const int nid = (orig & 7) * 32 + (orig >> 3);
  const int row0 = (nid >> 3) * 128, col0 = (nid & 7) * 128;
  const int lr = lane & 15, kq = lane >> 4;
  const int srow_lo = lane >> 3;
  const int scg = (lane & 7) ^ srow_lo;
  const unsigned short* Ab = A + (size_t)row0 * 1024;
  const unsigned short* Bb = Bt + (size_t)col0 * 1024;
  f32x4 acc[4][2] = {};

#define SP(bs, kt)                                                               \
  {                                                                              \
    const unsigned short* Ap = Ab + (kt) * 64;                                   \
    const unsigned short* Bp = Bb + (kt) * 64;                                   \
    _Pragma("unroll") for (int i = 0; i < 2; ++i) {                              \
      int g = wid * 2 + i;                                                       \
      int rrel = g * 8 + srow_lo;                                                \
      gload16(&Ap[(size_t)rrel * 1024 + scg * 8], &Abuf[bs][g * 512]);           \
      gload16(&Bp[(size_t)rrel * 1024 + scg * 8], &Bbuf[bs][g * 512]);           \
    }                                                                            \
  }
#define RPA(dst, mh)                                                             \
  _Pragma("unroll") for (int m = 0; m < 2; ++m)                                  \
  _Pragma("unroll") for (int ks = 0; ks < 2; ++ks) {                             \
    int row = wm * 64 + (mh) * 32 + m * 16 + lr;                                 \
    dst[m][ks] = *reinterpret_cast<const bf16x8*>(                               \
        &Ac[row * 64 + (((ks * 4 + kq) ^ (row & 7)) << 3)]);                     \
  }
#define RPB(dst)                                                                 \
  _Pragma("unroll") for (int n = 0; n < 2; ++n)                                  \
  _Pragma("unroll") for (int ks = 0; ks < 2; ++ks) {                             \
    int row = wn * 32 + n * 16 + lr;                                             \
    dst[n][ks] = *reinterpret_cast<const bf16x8*>(                               \
        &Bc[row * 64 + (((ks * 4 + kq) ^ (row & 7)) << 3)]);                     \
  }
#define PMM(mh, afv, bfv)                                                        \
  _Pragma("unroll") for (int m = 0; m < 2; ++m)                                  \
  _Pragma("unroll") for (int n = 0; n < 2; ++n)                                  \
  _Pragma("unroll") for (int ks = 0; ks < 2; ++ks)                               \
    acc[(mh) * 2 + m][n] = __builtin_amdgcn_mfma_f32_16x16x32_bf16(              \
        afv[m][ks], bfv[n][ks], acc[(mh) * 2 + m][n], 0, 0, 0);
#define BARP __builtin_amdgcn_s_barrier();

  SP(0, 0)
  asm volatile("s_waitcnt vmcnt(0)" ::: "memory");
  BARP
  __builtin_amdgcn_sched_barrier(0);

  for (int kt = 0; kt < 16; ++kt) {
    const int buf = kt & 1;
    const unsigned short* Ac = Abuf[buf];
    const unsigned short* Bc = Bbuf[buf];
    bf16x8 af0[2][2], af1[2][2], bfv[2][2];
    RPA(af0, 0) RPB(bfv)
    if (kt < 15) SP(buf ^ 1, kt + 1)
    BARP
    __builtin_amdgcn_s_setprio(1); PMM(0, af0, bfv) __builtin_amdgcn_s_setprio(0);
    BARP
    RPA(af1, 1)
    BARP
    __builtin_amdgcn_s_setprio(1); PMM(1, af1, bfv) __builtin_amdgcn_s_setprio(0);
    if (kt < 15) { asm volatile("s_waitcnt vmcnt(0)" ::: "memory"); }
    BARP
    __builtin_amdgcn_sched_barrier(0);
  }
#undef SP
#undef RPA
#undef RPB
#undef PMM
#undef BARP

  const int rbase = (lane >> 4) * 4;
#pragma unroll
  for (int mm = 0; mm < 4; ++mm) {
#pragma unroll
    for (int nn = 0; nn < 2; ++nn) {
      int c = col0 + wn * 32 + nn * 16 + lr;
      float bv = bias[c];
#pragma unroll
      for (int r = 0; r < 4; ++r) {
        int m = row0 + wm * 64 + mm * 16 + rbase + r;
        out[(size_t)m * 1024 + c] = acc[mm][nn][r] + bv;
      }
    }
  }
}

// ---------------- Flash attention (round-16 known-good): 8 waves = 4 q-subtiles x 2 key-halves.
// K+V in LDS (full-rank swizzle), double-buffered, ONE barrier/iter, fixed-ref softmax.
__global__ __launch_bounds__(512, 4) void attn_kernel(
    const unsigned short* __restrict__ qw, const unsigned short* __restrict__ kw,
    const unsigned short* __restrict__ vtg, unsigned short* __restrict__ ow) {
  __shared__ char smem[65536];
  unsigned short* KV = (unsigned short*)smem;
  unsigned short* Ol = (unsigned short*)smem;
  float* EX = (float*)(smem + 18432);
  const int t = threadIdx.x, lane = t & 63, wid = t >> 6;
  const int half = wid >> 2, wq = wid & 3;
  const int l31 = lane & 31, hi = lane >> 5;
  const int orig = blockIdx.x + 16 * blockIdx.y;
  const int nid = (orig & 7) * 64 + (orig >> 3);
  const int qt = nid & 15, bh = nid >> 4;
  const int b = bh >> 4, h = bh & 15;
  const unsigned short* Qg = qw + (size_t)bh * 2048 * 64;
  const unsigned short* Kg = kw + (size_t)bh * 2048 * 64;
  const unsigned short* Vg = vtg + (size_t)bh * 32 * 4096;
  const int q0 = qt * 128 + wq * 32;

  bf16x8 qf[4];
#pragma unroll
  for (int kc = 0; kc < 4; ++kc)
    qf[kc] = *reinterpret_cast<const bf16x8*>(&Qg[(q0 + l31) * 64 + kc * 16 + hi * 8]);

  f32x16 oA = {0,0,0,0,0,0,0,0,0,0,0,0,0,0,0,0};
  f32x16 oB = {0,0,0,0,0,0,0,0,0,0,0,0,0,0,0,0};
  float lrun = 0.f;

  const int srow_lo = lane >> 3;
  const int scg0 = (lane & 7) ^ srow_lo;
  const int rsw = (l31 & 7) ^ ((l31 >> 3) & 3);

#define STAGE(buf, kt)                                                              \
  {                                                                                 \
    const unsigned short* Kt = Kg + (size_t)(kt) * 4096;                            \
    const unsigned short* Vs = Vg + (size_t)(kt) * 4096;                            \
    unsigned short* Kl = KV + half * 16384 + (buf) * 8192;                          \
    unsigned short* Vl = Kl + 4096;                                                 \
    _Pragma("unroll") for (int i = 0; i < 2; ++i) {                                 \
      int chunk = wq * 2 + i;                                                       \
      int row = chunk * 8 + srow_lo;                                                \
      int sc = (scg0 ^ (chunk & 3)) * 8;                                            \
      gload16(&Kt[row * 64 + sc], &Kl[chunk * 512]);                                \
      gload16(&Vs[row * 64 + sc], &Vl[chunk * 512]);                                \
    }                                                                               \
  }

  const int kt0 = half * 16;
  STAGE(0, kt0)

  for (int it = 0; it < 16; ++it) {
    const int cur = it & 1;
    asm volatile("s_waitcnt vmcnt(0)" ::: "memory");
    __builtin_amdgcn_s_barrier();
    if (it + 1 < 16) STAGE(cur ^ 1, kt0 + it + 1)
    const unsigned short* Kl = KV + half * 16384 + cur * 8192;
    const unsigned short* Vl = Kl + 4096;

    f32x16 sA = {0,0,0,0,0,0,0,0,0,0,0,0,0,0,0,0};
    f32x16 sB = {0,0,0,0,0,0,0,0,0,0,0,0,0,0,0,0};
    __builtin_amdgcn_s_setprio(1);
#pragma unroll
    for (int kc = 0; kc < 4; ++kc) {
      bf16x8 k0f = *reinterpret_cast<const bf16x8*>(
          &Kl[l31 * 64 + (((kc * 2 + hi) ^ rsw) << 3)]);
      bf16x8 k1f = *reinterpret_cast<const bf16x8*>(
          &Kl[(32 + l31) * 64 + (((kc * 2 + hi) ^ rsw) << 3)]);
      sA = __builtin_amdgcn_mfma_f32_32x32x16_bf16(k0f, qf[kc], sA, 0, 0, 0);
      sB = __builtin_amdgcn_mfma_f32_32x32x16_bf16(k1f, qf[kc], sB, 0, 0, 0);
    }
    __builtin_amdgcn_s_setprio(0);

    float rsv[16];
#pragma unroll
    for (int j = 0; j < 16; ++j) {
      float pa = exp2f(sA[j]);
      float pb = exp2f(sB[j]);
      sA[j] = pa; sB[j] = pb;
      rsv[j] = pa + pb;
    }
#pragma unroll
    for (int s = 8; s >= 1; s >>= 1)
#pragma unroll
      for (int j = 0; j < s; ++j) rsv[j] += rsv[j + s];
    lrun += rsv[0] + __shfl_xor(rsv[0], 32);

    bf16x8 pf0 = pack_pfrag<0>(sA);
    bf16x8 pf1 = pack_pfrag<8>(sA);
    bf16x8 pf2 = pack_pfrag<0>(sB);
    bf16x8 pf3 = pack_pfrag<8>(sB);

    __builtin_amdgcn_s_setprio(1);
#pragma unroll
    for (int c = 0; c < 4; ++c) {
      bf16x8 pf = (c == 0) ? pf0 : (c == 1) ? pf1 : (c == 2) ? pf2 : pf3;
      int g = c * 2 + hi;
      bf16x8 v0f = *reinterpret_cast<const bf16x8*>(
          &Vl[l31 * 64 + ((g ^ rsw) << 3)]);
      bf16x8 v1f = *reinterpret_cast<const bf16x8*>(
          &Vl[(32 + l31) * 64 + ((g ^ rsw) << 3)]);
      oA = __builtin_amdgcn_mfma_f32_32x32x16_bf16(v0f, pf, oA, 0, 0, 0);
      oB = __builtin_amdgcn_mfma_f32_32x32x16_bf16(v1f, pf, oB, 0, 0, 0);
    }
    __builtin_amdgcn_s_setprio(0);
  }
#undef STAGE

  __syncthreads();
  if (half == 1) {
    float* e = EX + ((size_t)(wq * 64 + lane)) * 34;
#pragma unroll
    for (int j = 0; j < 16; ++j) { e[j] = oA[j]; e[16 + j] = oB[j]; }
    e[32] = lrun;
  }
  __syncthreads();
  if (half == 0) {
    const float* e = EX + ((size_t)(wq * 64 + lane)) * 34;
    float linv = 1.0f / (lrun + e[32]);
    unsigned short* orow_l = Ol + (wq * 32 + l31) * 72;
#pragma unroll
    for (int g = 0; g < 4; ++g) {
      float a0 = (oA[4 * g + 0] + e[4 * g + 0]) * linv;
      float a1v = (oA[4 * g + 1] + e[4 * g + 1]) * linv;
      float a2v = (oA[4 * g + 2] + e[4 * g + 2]) * linv;
      float a3v = (oA[4 * g + 3] + e[4 * g + 3]) * linv;
      uint2 w0; w0.x = cvtpk(a0, a1v); w0.y = cvtpk(a2v, a3v);
      *reinterpret_cast<uint2*>(&orow_l[8 * g + 4 * hi]) = w0;
      float b0 = (oB[4 * g + 0] + e[16 + 4 * g + 0]) * linv;
      float b1v = (oB[4 * g + 1] + e[16 + 4 * g + 1]) * linv;
      float b2v = (oB[4 * g + 2] + e[16 + 4 * g + 2]) * linv;
      float b3v = (oB[4 * g + 3] + e[16 + 4 * g + 3]) * linv;
      uint2 w1; w1.x = cvtpk(b0, b1v); w1.y = cvtpk(b2v, b3v);
      *reinterpret_cast<uint2*>(&orow_l[32 + 8 * g + 4 * hi]) = w1;
    }
  }
  __syncthreads();
#pragma unroll
  for (int i = 0; i < 2; ++i) {
    int idx = t + i * 512;
    int q = idx >> 3, ch = idx & 7;
    int4 v = *reinterpret_cast<const int4*>(&Ol[q * 72 + ch * 8]);
    *reinterpret_cast<int4*>(
        &ow[(((size_t)b * 2048 + qt * 128 + q) * 16 + h) * 64 + ch * 8]) = v;
  }
}

extern "C" void kernel_launch(void* const* d_in, const int* in_sizes, int n_in,
                              void* d_out, int out_size, void* d_ws, size_t ws_size,
                              hipStream_t stream) {
  const float* hs = (const float*)d_in[0];
  const float* w_attn = (const float*)d_in[1];
  const float* b_attn = (const float*)d_in[2];
  const float* w_proj = (const float*)d_in[3];
  const float* b_proj = (const float*)d_in[4];
  float* out = (float*)d_out;

  const size_t HEAD = (size_t)2 * 16 * 2048 * 64;
  unsigned short* qw = (unsigned short*)d_ws;
  unsigned short* kw = qw + HEAD;
  unsigned short* vtg = kw + HEAD;
  unsigned short* hs_b = vtg + HEAD;
  unsigned short* ow = hs_b;
  unsigned short* wT = hs_b + HEAD;
  unsigned short* pT = wT + (size_t)3072 * 1024;

  prep_fused<<<dim3(2048), 256, 0, stream>>>(hs, hs_b, w_attn, wT, w_proj, pT);

  gemm_qkv_8p<<<dim3(256), 512, 0, stream>>>(hs_b, wT, b_attn, qw, kw, vtg);
  attn_kernel<<<dim3(16, 32), 512, 0, stream>>>(qw, kw, vtg, ow);
  gemm_proj_8p<<<dim3(256), 512, 0, stream>>>(ow, pT, b_proj, out);
}